// Round 1
// baseline (705.939 us; speedup 1.0000x reference)
//
#include <hip/hip_runtime.h>

typedef __attribute__((ext_vector_type(4))) float f32x4;
typedef __attribute__((ext_vector_type(8))) short s16x8;

#define NHEAD 8

__device__ __forceinline__ ushort f2bf(float f) {
  union { float f; uint u; } v; v.f = f;
  uint r = v.u + 0x7fffu + ((v.u >> 16) & 1u);
  return (ushort)(r >> 16);
}

struct WSrc { const float* p[8]; };

// Transpose fp32 [*,256,256] (f-major) -> bf16 [*,256,256] (g-major) so the
// hot kernel's B-fragments read contiguous-k.
__global__ __launch_bounds__(256) void prep_weights(WSrc s, ushort* wq, ushort* wo) {
  int mm = blockIdx.x >> 6;          // 0..15: axis*4 + {0,1,2:qkv mats, 3:wo}
  int t  = blockIdx.x & 63;
  int a = mm >> 2, sub = mm & 3;
  const float* src = (sub < 3) ? (s.p[a*2] + sub*65536) : s.p[a*2+1];
  ushort*      dst = (sub < 3) ? (wq + (a*3 + sub)*65536) : (wo + a*65536);
  int gt = (t >> 3) * 32, ft = (t & 7) * 32;
  __shared__ float tile[32][33];
  int lx = threadIdx.x & 31, ly = threadIdx.x >> 5;
#pragma unroll
  for (int i = 0; i < 4; i++)
    tile[ly + i*8][lx] = src[(ft + ly + i*8)*256 + gt + lx];
  __syncthreads();
#pragma unroll
  for (int i = 0; i < 4; i++)
    dst[(gt + ly + i*8)*256 + ft + lx] = f2bf(tile[lx][ly + i*8]);
}

template<int AXIS>
__device__ __forceinline__ int token_index(int blk, int row) {
  if (AXIS == 0) {                       // temporal: 8 seqs/block, 2 per wave
    int seq = blk*8 + (row >> 3);
    int t = row & 7;
    int b = seq >> 12, n = seq & 4095;
    return (b*8 + t)*4096 + n;
  } else {
    int sid = blk*4 + (row >> 4);        // 4 seqs/block, 1 per wave
    int bt = sid >> 8, lo = sid & 255, r = row & 15;
    if (AXIS == 1) { int hh = lo >> 4, ww = lo & 15; return bt*4096 + r*256 + hh*16 + ww; }
    if (AXIS == 2) { int dd = lo >> 4, ww = lo & 15; return bt*4096 + dd*256 + r*16 + ww; }
    { int dd = lo >> 4, hh = lo & 15; return bt*4096 + dd*256 + hh*16 + r; }
  }
}

template<int AXIS>
__global__ __launch_bounds__(256, 1) void axial_pass(
    const float* __restrict__ x0, const ushort* __restrict__ xb,
    const ushort* __restrict__ wqkvT, const float* __restrict__ bqkv,
    const ushort* __restrict__ woT, const float* __restrict__ bo,
    float* __restrict__ out, ushort* __restrict__ x1b) {

  __shared__ s16x8 XsV[64][33];    // X tile [64 tok][256 k], pitch 264
  __shared__ s16x8 WsV[32][33];    // qkv weight chunk [32 n][256 k]
  __shared__ s16x8 WoSV[256][5];   // out-proj chunk  [256 n][32 k], pitch 40
  __shared__ s16x8 QsV[64][5];     // per-wave Q [16 s][32 d]
  __shared__ s16x8 KsV[64][5];     // per-wave K [16 t][32 d]
  __shared__ s16x8 VtsV[128][5];   // per-wave V^T [32 d][16 t + zero pad to 32]
  __shared__ s16x8 PsV[64][5];     // per-wave P [16 s][16 t + zero pad to 32]
  __shared__ s16x8 AsV[64][5];     // per-wave attn [16 s][32 d]
  __shared__ float bq_s[3*256];
  __shared__ float bo_s[256];

  ushort* Xs_u  = (ushort*)XsV;
  ushort* Ws_u  = (ushort*)WsV;
  ushort* WoS_u = (ushort*)WoSV;
  ushort* Qs_u  = (ushort*)QsV;
  ushort* Ks_u  = (ushort*)KsV;
  ushort* Vts_u = (ushort*)VtsV;
  ushort* Ps_u  = (ushort*)PsV;
  ushort* As_u  = (ushort*)AsV;

  const int tid = threadIdx.x;
  const int blk = blockIdx.x;
  const int wv = tid >> 6, lane = tid & 63, llo = lane & 15, lhi = lane >> 4;
  const f32x4 fzero = {0.f, 0.f, 0.f, 0.f};

  bo_s[tid] = bo[tid];
#pragma unroll
  for (int j = 0; j < 3; j++) bq_s[j*256 + tid] = bqkv[j*256 + tid];

  // zero the k-padding of P and V^T (cols 16..31) once; never rewritten
  for (int i = tid; i < 64*16; i += 256)  Ps_u[(i >> 4)*40 + 16 + (i & 15)] = 0;
  for (int i = tid; i < 128*16; i += 256) Vts_u[(i >> 4)*40 + 16 + (i & 15)] = 0;

  // stage X tile (convert fp32->bf16 for axis 0; bf16 passthrough otherwise)
  {
    int row = tid >> 2, q = tid & 3;
    int tok = token_index<AXIS>(blk, row);
    if (AXIS == 0) {
      const float4* s4 = (const float4*)(x0 + (size_t)tok*256 + q*64);
      ushort4* d4 = (ushort4*)(Xs_u + row*264 + q*64);
#pragma unroll
      for (int i = 0; i < 16; i++) {
        float4 v = s4[i];
        ushort4 o; o.x = f2bf(v.x); o.y = f2bf(v.y); o.z = f2bf(v.z); o.w = f2bf(v.w);
        d4[i] = o;
      }
    } else {
      const uint4* s4 = (const uint4*)(xb + (size_t)tok*256 + q*64);
      uint4* d4 = (uint4*)(Xs_u + row*264 + q*64);
#pragma unroll
      for (int i = 0; i < 8; i++) d4[i] = s4[i];
    }
  }
  __syncthreads();

  f32x4 acc[16];
#pragma unroll
  for (int i = 0; i < 16; i++) acc[i] = fzero;

  const int xrow = wv*16 + llo;

  for (int h = 0; h < NHEAD; h++) {
    // ---- qkv projection: per matrix m, stage W chunk [32n x 256k], MFMA ----
    for (int m = 0; m < 3; m++) {
      __syncthreads();
      {
        int n = tid >> 3, j = tid & 7;
        const uint4* src = (const uint4*)(wqkvT + m*65536 + (h*32 + n)*256 + j*32);
        uint4* dst = (uint4*)(Ws_u + n*264 + j*32);
#pragma unroll
        for (int i = 0; i < 4; i++) dst[i] = src[i];
      }
      __syncthreads();
#pragma unroll
      for (int nt = 0; nt < 2; nt++) {
        f32x4 c = fzero;
#pragma unroll
        for (int ks = 0; ks < 8; ks++) {
          s16x8 av = XsV[xrow][ks*4 + lhi];
          s16x8 bv = WsV[nt*16 + llo][ks*4 + lhi];
          c = __builtin_amdgcn_mfma_f32_16x16x32_bf16(av, bv, c, 0, 0, 0);
        }
        float bias = bq_s[m*256 + h*32 + nt*16 + llo];
#pragma unroll
        for (int r = 0; r < 4; r++) {
          ushort bvv = f2bf(c[r] + bias);
          int srow = lhi*4 + r;
          if (m == 0)      Qs_u[(wv*16 + srow)*40 + nt*16 + llo] = bvv;
          else if (m == 1) Ks_u[(wv*16 + srow)*40 + nt*16 + llo] = bvv;
          else             Vts_u[(wv*32 + nt*16 + llo)*40 + srow] = bvv;  // transposed
        }
      }
    }
    __syncthreads();
    { // stage Wo head-rows transposed: WoS[n 0..255][k 0..31]
      const uint4* src = (const uint4*)(woT + tid*256 + h*32);
      uint4* dst = (uint4*)(WoS_u + tid*40);
#pragma unroll
      for (int i = 0; i < 4; i++) dst[i] = src[i];
    }
    __syncthreads();

    // ---- scores = Q K^T / sqrt(32), softmax over t (wave-parallel) ----
    {
      s16x8 aq = QsV[wv*16 + llo][lhi];
      s16x8 bk = KsV[wv*16 + llo][lhi];
      f32x4 sc = __builtin_amdgcn_mfma_f32_16x16x32_bf16(aq, bk, fzero, 0, 0, 0);
#pragma unroll
      for (int r = 0; r < 4; r++) {
        float s = sc[r] * 0.17677669529663689f;
        if (AXIS == 0) {  // two packed length-8 sequences: block-diagonal mask
          int srow = lhi*4 + r;
          if ((srow >> 3) != (llo >> 3)) s = -1e30f;
        }
        float mx = s;
        mx = fmaxf(mx, __shfl_xor(mx, 1));
        mx = fmaxf(mx, __shfl_xor(mx, 2));
        mx = fmaxf(mx, __shfl_xor(mx, 4));
        mx = fmaxf(mx, __shfl_xor(mx, 8));
        float e = __expf(s - mx);
        float sm = e;
        sm += __shfl_xor(sm, 1);
        sm += __shfl_xor(sm, 2);
        sm += __shfl_xor(sm, 4);
        sm += __shfl_xor(sm, 8);
        Ps_u[(wv*16 + lhi*4 + r)*40 + llo] = f2bf(e / sm);
      }
    }
    // ---- PV ----
    {
      s16x8 ap = PsV[wv*16 + llo][lhi];
#pragma unroll
      for (int nt = 0; nt < 2; nt++) {
        s16x8 bv = VtsV[wv*32 + nt*16 + llo][lhi];
        f32x4 c = __builtin_amdgcn_mfma_f32_16x16x32_bf16(ap, bv, fzero, 0, 0, 0);
#pragma unroll
        for (int r = 0; r < 4; r++)
          As_u[(wv*16 + lhi*4 + r)*40 + nt*16 + llo] = f2bf(c[r]);
      }
    }
    // ---- out-proj accumulate: acc += attn_h @ Wo[h*32:h*32+32, :] ----
    {
      s16x8 aa = AsV[wv*16 + llo][lhi];
#pragma unroll
      for (int nt = 0; nt < 16; nt++) {
        s16x8 bw = WoSV[nt*16 + llo][lhi];
        acc[nt] = __builtin_amdgcn_mfma_f32_16x16x32_bf16(aa, bw, acc[nt], 0, 0, 0);
      }
    }
  }

  // ---- epilogue: +bo, residual handling ----
#pragma unroll
  for (int r = 0; r < 4; r++) {
    int row = wv*16 + lhi*4 + r;
    int tok = token_index<AXIS>(blk, row);
    size_t base = (size_t)tok*256;
#pragma unroll
    for (int nt = 0; nt < 16; nt++) {
      int f = nt*16 + llo;
      float v = acc[nt][r] + bo_s[f];
      if (AXIS == 0) {
        v += x0[base + f];
        out[base + f] = v;          // x1 (fp32)
        x1b[base + f] = f2bf(v);    // x1 (bf16) for spatial passes
      } else {
        out[base + f] += v;         // accumulate axis contribution
      }
    }
  }
}

extern "C" void kernel_launch(void* const* d_in, const int* in_sizes, int n_in,
                              void* d_out, int out_size, void* d_ws, size_t ws_size,
                              hipStream_t stream) {
  const float* x = (const float*)d_in[0];
  ushort* wq  = (ushort*)d_ws;                 // 4*3*65536 bf16
  ushort* wo  = wq + 4*3*65536;                // 4*65536 bf16
  ushort* x1b = wo + 4*65536;                  // 65536*256 bf16
  float* out = (float*)d_out;

  WSrc wsrc;
  wsrc.p[0] = (const float*)d_in[1];  wsrc.p[1] = (const float*)d_in[3];
  wsrc.p[2] = (const float*)d_in[5];  wsrc.p[3] = (const float*)d_in[7];
  wsrc.p[4] = (const float*)d_in[9];  wsrc.p[5] = (const float*)d_in[11];
  wsrc.p[6] = (const float*)d_in[13]; wsrc.p[7] = (const float*)d_in[15];
  prep_weights<<<dim3(1024), dim3(256), 0, stream>>>(wsrc, wq, wo);

  const float* bq_t = (const float*)d_in[2];  const float* bo_t = (const float*)d_in[4];
  const float* bq_d = (const float*)d_in[6];  const float* bo_d = (const float*)d_in[8];
  const float* bq_h = (const float*)d_in[10]; const float* bo_h = (const float*)d_in[12];
  const float* bq_w = (const float*)d_in[14]; const float* bo_w = (const float*)d_in[16];

  axial_pass<0><<<dim3(1024), dim3(256), 0, stream>>>(x, nullptr, wq + 0*3*65536, bq_t, wo + 0*65536, bo_t, out, x1b);
  axial_pass<1><<<dim3(1024), dim3(256), 0, stream>>>(nullptr, x1b, wq + 1*3*65536, bq_d, wo + 1*65536, bo_d, out, nullptr);
  axial_pass<2><<<dim3(1024), dim3(256), 0, stream>>>(nullptr, x1b, wq + 2*3*65536, bq_h, wo + 2*65536, bo_h, out, nullptr);
  axial_pass<3><<<dim3(1024), dim3(256), 0, stream>>>(nullptr, x1b, wq + 3*3*65536, bq_w, wo + 3*65536, bo_w, out, nullptr);
}